// Round 8
// baseline (147.322 us; speedup 1.0000x reference)
//
#include <hip/hip_runtime.h>
#include <math.h>

typedef unsigned int u32;
typedef unsigned long long u64;

#define N_ELEM 131072
#define NBIN 16384         // 14-bit key-space bins (min-key only)
#define BSH 18             // key >> 18 -> bin
#define CAP 2048           // candidate capacity per array (typ. ~100 used)
#define SCAN_CAP 64        // max bins scanned upward in successor proof
#define GMARG 0.0999       // conservative gap margin (< 0.1*(1-1e-9))
#define GRID 256           // persistent blocks (64 KB LDS -> 2/CU, co-resident)
#define BS 256
#define NBA 128            // data blocks per array
#define EPB 1024           // elements per block in data phases

// ascending-sortable key: monotone bijection f32 -> u32
__device__ __forceinline__ u32 kasc(float x) {
  u32 u = __float_as_uint(x);
  return (u & 0x80000000u) ? ~u : (u | 0x80000000u);
}
__device__ __forceinline__ float kasc2f(u32 t) {
  return __uint_as_float((t & 0x80000000u) ? (t ^ 0x80000000u) : ~t);
}

// device-scope grid barrier (cg grid.sync protocol). Counters zeroed by
// hipMemsetAsync before every launch (replayed in the graph -> stateless).
__device__ __forceinline__ void gbar(u32* bars, int idx) {
  __syncthreads();
  if (threadIdx.x == 0) {
    __threadfence();                      // release
    atomicAdd(&bars[idx], 1u);
    while (atomicAdd(&bars[idx], 0u) < (u32)GRID) __builtin_amdgcn_s_sleep(2);
    __threadfence();                      // acquire
  }
  __syncthreads();
}

__global__ __launch_bounds__(256) void k_mega(
    const float* __restrict__ in0, const float* __restrict__ in1,
    u32* binMinK, u32* candCnt, float* candVal,
    u32* pCnt, double* pSum, float* segV, double* segS, int* segN,
    double* part, u32* bars, float* out) {
  __shared__ union {
    u32 lmn[NBIN];                                                   // 64 KB (B, C)
    float lv[EPB];                                                   // 4 KB  (D)
    struct { int sp[CAP]; float svv[CAP]; int dp[CAP]; float dv[CAP];
             double scv[CAP]; double dc[CAP]; } hu;                  // 64 KB (E)
    struct { float lv0[CAP]; float lv1[CAP];
             double ls0[CAP]; double ls1[CAP];
             double s0[BS]; double s1[BS]; double s2[BS]; } rm;      // 54 KB (F)
  } S;
  __shared__ int sh_ntop;
  const int blk = blockIdx.x, t = threadIdx.x;
  const int arr = blk >> 7, b = blk & 127;
  const float* pin = arr ? in1 : in0;

  // ---- phase A: init global bin mins + candidate counters ----
  {
    int i = blk * BS + t;
    if (i < 2 * NBIN) binMinK[i] = 0xFFFFFFFFu;
    if (i < 2) candCnt[i] = 0u;
  }
  gbar(bars, 0);

  // ---- phase B: exact per-bin MIN key (LDS-staged; nonempty <=> min != ~0) ----
  for (int k = t; k < NBIN; k += BS) S.lmn[k] = 0xFFFFFFFFu;
  __syncthreads();
  {
    float4 v = ((const float4*)(pin + b * EPB))[t];  // 256 x float4 = 1024 elems
    float xs[4] = {v.x, v.y, v.z, v.w};
#pragma unroll
    for (int e = 0; e < 4; e++) {
      u32 k = kasc(xs[e]);
      atomicMin(&S.lmn[k >> BSH], k);   // LDS atomics: order-independent
    }
  }
  __syncthreads();
  {
    u32* bmn = binMinK + arr * NBIN;
    for (int k = t; k < NBIN; k += BS) {
      u32 mn = S.lmn[k];
      if (mn != 0xFFFFFFFFu) atomicMin(&bmn[k], mn);  // flush nonempty only
    }
  }
  gbar(bars, 1);

  // ---- phase C: candidate detection (bin table staged back into LDS) ----
  // Flag x unless we can PROVE an element exists in (x, x+GMARG] (then the
  // sorted gap above x's run is < reg -> x cannot be a hull vertex; rigorous:
  // vertex at p => y_{p-1} > y_p => gap > reg). Proof source: first nonempty
  // higher bin's exact min (any key in a higher bin is strictly > x). Dense
  // regions always prove (next-bin min within 2*binwidth <= 0.0625 < GMARG);
  // sparse tails over-include, and the exact f64 hull discards non-vertices.
  {
    const uint4* g4 = (const uint4*)(binMinK + arr * NBIN);
    for (int k = t; k < NBIN / 4; k += BS) ((uint4*)S.lmn)[k] = g4[k];
    __syncthreads();
    if (b == 0 && t == 0) {  // right-endpoint sentinel: p = N (counts everything)
      u32 s = atomicAdd(&candCnt[arr], 1u);
      if (s < CAP) candVal[arr * CAP + s] = -INFINITY;
    }
    float4 v4 = ((const float4*)(pin + b * EPB))[t];
    float xs[4] = {v4.x, v4.y, v4.z, v4.w};
    for (int e = 0; e < 4; e++) {
      float x = xs[e];
      double xd = (double)x;
      u32 bn = kasc(x) >> BSH;
      bool proven = false;
      for (int it = 0; it < SCAN_CAP; it++) {
        bn++;
        if (bn >= NBIN) break;                    // nothing above -> flag (max elem)
        double lb = (double)kasc2f(bn << BSH);    // bin lower-boundary value
        if (lb > xd + GMARG) break;               // all further mins > x+G -> flag
        u32 mn = S.lmn[bn];
        if (mn != 0xFFFFFFFFu) {
          proven = ((double)kasc2f(mn) - xd <= GMARG);
          break;
        }
      }
      if (!proven) {
        u32 s = atomicAdd(&candCnt[arr], 1u);
        if (s < CAP) candVal[arr * CAP + s] = x;
      }
    }
  }
  gbar(bars, 2);

  // ---- phase D: per-block masked count/sum per candidate threshold ----
  // count_j = #{x > v_j}, sum_j = sum{x > v_j}; fixed shuffle tree.
  {
    ((float4*)S.lv)[t] = ((const float4*)(pin + b * EPB))[t];
    __syncthreads();
    int lane = t & 63, w = t >> 6;
    u32 cc = candCnt[arr];
    int cnt = (int)(cc < (u32)CAP ? cc : (u32)CAP);
    for (int j = w; j < cnt; j += 4) {
      float v = candVal[arr * CAP + j];
      int c = 0;
      double s = 0.0;
      for (int e = lane; e < EPB; e += 64) {
        float x = S.lv[e];
        if (x > v) { c++; s += (double)x; }
      }
#pragma unroll
      for (int o = 32; o > 0; o >>= 1) {
        c += __shfl_down(c, o);
        s += __shfl_down(s, o);
      }
      if (lane == 0) {
        pCnt[((size_t)(arr * NBA + b)) * CAP + j] = (u32)c;
        pSum[((size_t)(arr * NBA + b)) * CAP + j] = s;
      }
    }
  }
  gbar(bars, 3);

  // ---- phase E: reduce partials -> (p, C[p]); sort by p; monotone chain ----
  if (blk < 2) {
    int a2 = blk;
    u32 cc = candCnt[a2];
    int cnt = (int)(cc < (u32)CAP ? cc : (u32)CAP);
    for (int j = t; j < cnt; j += BS) {
      long long c = 0;
      double s = 0.0;
      for (int bb = 0; bb < NBA; bb++) {  // fixed order -> deterministic
        c += (long long)pCnt[((size_t)(a2 * NBA + bb)) * CAP + j];
        s += pSum[((size_t)(a2 * NBA + bb)) * CAP + j];
      }
      double pd = (double)c;
      // C[p] = S_p/reg - (p*n - p(p-1)/2), exact in f64
      S.hu.sp[j] = (int)c;
      S.hu.scv[j] = s / 0.1 - (pd * (double)N_ELEM - pd * (pd - 1.0) * 0.5);
      S.hu.svv[j] = candVal[a2 * CAP + j];
    }
    __syncthreads();
    // rank sort by (p, slot); equal-p records have identical (p,C) and the kept
    // value provably cannot change any ELEMENT's segment classification
    for (int j = t; j < cnt; j += BS) {
      int pj = S.hu.sp[j], rk = 0;
      for (int k = 0; k < cnt; k++) {
        int pk = S.hu.sp[k];
        rk += (pk < pj) || (pk == pj && k < j);
      }
      S.hu.dp[rk] = pj; S.hu.dc[rk] = S.hu.scv[j]; S.hu.dv[rk] = S.hu.svv[j];
    }
    __syncthreads();
    if (t == 0) {
      int top = 0, aX = 0, bX = 0, prevP = -1;
      double cA = 0.0, cB = 0.0;
      for (int k = 0; k < cnt; k++) {
        int i = S.hu.dp[k];
        if (i == prevP) continue;  // dedupe identical diagram points
        prevP = i;
        double Ci = S.hu.dc[k];
        float vi = S.hu.dv[k];
        while (top >= 2) {
          double cr = (double)(bX - aX) * (Ci - cA) - (cB - cA) * (double)(i - aX);
          if (cr >= 0.0) {  // bX on/below chord aX->i : pop
            top--;
            bX = aX; cB = cA;
            if (top >= 2) { aX = S.hu.dp[top - 2]; cA = S.hu.dc[top - 2]; }
          } else break;
        }
        S.hu.dp[top] = i; S.hu.dc[top] = Ci; S.hu.dv[top] = vi;
        aX = bX; cA = cB;
        bX = i;  cB = Ci;
        top++;
      }
      sh_ntop = top;
    }
    __syncthreads();
    int top = sh_ntop;
    for (int k = t; k < top - 1; k += BS) {
      segV[a2 * CAP + k] = S.hu.dv[k];  // left-vertex value (descending)
      segS[a2 * CAP + k] = (S.hu.dc[k + 1] - S.hu.dc[k]) / (double)(S.hu.dp[k + 1] - S.hu.dp[k]);
    }
    if (t == 0) segN[a2] = top - 1;
  }
  gbar(bars, 4);

  // ---- phase F: fused rank + centered moments ----
  // x in segment k iff v_k >= x > v_{k+1}; rank = x/reg - slope_k. Mean is
  // analytic: permutahedron projection preserves sum -> mean = (N+1)/2.
  {
    int n0 = segN[0], n1 = segN[1];
    for (int k = t; k < n0; k += BS) { S.rm.lv0[k] = segV[k]; S.rm.ls0[k] = segS[k]; }
    for (int k = t; k < n1; k += BS) { S.rm.lv1[k] = segV[CAP + k]; S.rm.ls1[k] = segS[CAP + k]; }
    __syncthreads();
    const double m = 0.5 * (double)(N_ELEM + 1);  // 65536.5
    double a0 = 0.0, a1 = 0.0, a2 = 0.0;
    float2 x2 = ((const float2*)(in0 + blk * 512))[t];
    float2 y2 = ((const float2*)(in1 + blk * 512))[t];
    float xs[2] = {x2.x, x2.y};
    float ys[2] = {y2.x, y2.y};
#pragma unroll
    for (int e = 0; e < 2; e++) {
      float x = xs[e], y = ys[e];
      int k0 = 0, k1 = 0;
      for (int k = 1; k < n0; k++) if (x <= S.rm.lv0[k]) k0 = k;
      for (int k = 1; k < n1; k++) if (y <= S.rm.lv1[k]) k1 = k;
      double ra = (double)x / 0.1 - S.rm.ls0[k0] - m;
      double rb = (double)y / 0.1 - S.rm.ls1[k1] - m;
      a0 += ra * rb;
      a1 += ra * ra;
      a2 += rb * rb;
    }
    S.rm.s0[t] = a0; S.rm.s1[t] = a1; S.rm.s2[t] = a2;
    __syncthreads();
    for (int off = 128; off > 0; off >>= 1) {
      if (t < off) {
        S.rm.s0[t] += S.rm.s0[t + off];
        S.rm.s1[t] += S.rm.s1[t + off];
        S.rm.s2[t] += S.rm.s2[t + off];
      }
      __syncthreads();
    }
    if (t == 0) {
      part[blk] = S.rm.s0[0];
      part[GRID + blk] = S.rm.s1[0];
      part[2 * GRID + blk] = S.rm.s2[0];
    }
  }
  gbar(bars, 5);

  // ---- phase G: final reduction (one wave, fixed tree) ----
  if (blk == 0 && t < 64) {
    double v0 = 0.0, v1 = 0.0, v2 = 0.0;
    for (int k = t; k < GRID; k += 64) {
      v0 += part[k];
      v1 += part[GRID + k];
      v2 += part[2 * GRID + k];
    }
#pragma unroll
    for (int off = 32; off > 0; off >>= 1) {
      v0 += __shfl_down(v0, off);
      v1 += __shfl_down(v1, off);
      v2 += __shfl_down(v2, off);
    }
    if (t == 0) out[0] = (float)(v0 / (sqrt(v1) * sqrt(v2)));
  }
}

// ---------------- host ----------------
extern "C" void kernel_launch(void* const* d_in, const int* in_sizes, int n_in,
                              void* d_out, int out_size, void* d_ws, size_t ws_size,
                              hipStream_t stream) {
  const float* in0 = (const float*)d_in[0];
  const float* in1 = (const float*)d_in[1];
  float* out = (float*)d_out;

  size_t off = 0;
  char* base = (char*)d_ws;
  auto alloc = [&](size_t bytes) -> char* {
    char* p = base + off;
    off += (bytes + 63) & ~(size_t)63;
    return p;
  };
  u32* binMinK = (u32*)alloc(sizeof(u32) * 2 * NBIN);
  u32* candCnt = (u32*)alloc(sizeof(u32) * 2);
  float* candVal = (float*)alloc(sizeof(float) * 2 * CAP);
  u32* pCnt    = (u32*)alloc(sizeof(u32) * 2 * NBA * CAP);
  double* pSum = (double*)alloc(sizeof(double) * 2 * NBA * CAP);
  float* segV  = (float*)alloc(sizeof(float) * 2 * CAP);
  double* segS = (double*)alloc(sizeof(double) * 2 * CAP);
  int* segN    = (int*)alloc(sizeof(int) * 2);
  double* part = (double*)alloc(sizeof(double) * 3 * GRID);
  u32* bars    = (u32*)alloc(sizeof(u32) * 16);
  (void)ws_size; (void)in_sizes; (void)n_in; (void)out_size;

  // zero the barrier counters (replayed in the graph every iteration)
  hipMemsetAsync(bars, 0, sizeof(u32) * 16, stream);

  k_mega<<<dim3(GRID), dim3(256), 0, stream>>>(
      in0, in1, binMinK, candCnt, candVal,
      pCnt, pSum, segV, segS, segN, part, bars, out);
}

// Round 9
// 145.382 us; speedup vs baseline: 1.0133x; 1.0133x over previous
//
#include <hip/hip_runtime.h>
#include <math.h>

typedef unsigned int u32;
typedef unsigned long long u64;

#define N_ELEM 131072
#define NBIN 16384         // 14-bit key-space bins (min-key only)
#define BSH 18             // key >> 18 -> bin
#define CAP 2048           // candidate capacity per array (typ. ~100 used)
#define SCAN_CAP 64        // max bins scanned upward in successor proof
#define GMARG 0.0999       // conservative gap margin (< 0.1*(1-1e-9))
#define GRID 256           // persistent blocks (64 KB LDS -> co-resident on 256 CUs)
#define BS 256
#define NBA 128            // data blocks per array
#define EPB 1024           // elements per block in data phases

// ascending-sortable key: monotone bijection f32 -> u32
__device__ __forceinline__ u32 kasc(float x) {
  u32 u = __float_as_uint(x);
  return (u & 0x80000000u) ? ~u : (u | 0x80000000u);
}
__device__ __forceinline__ float kasc2f(u32 t) {
  return __uint_as_float((t & 0x80000000u) ? (t ^ 0x80000000u) : ~t);
}

// device-scope grid barrier (cooperative-groups grid.sync protocol).
// Arrive: release fence + atomicAdd (RMW, pipelined). Spin: coherent atomic
// LOAD (no RMW -> no serialization convoy) + s_sleep backoff. Counters are
// zeroed by hipMemsetAsync before every launch (replayed in graph -> stateless).
__device__ __forceinline__ void gbar(u32* bars, int idx) {
  __syncthreads();
  if (threadIdx.x == 0) {
    __threadfence();                      // release: make prior writes visible
    atomicAdd(&bars[idx], 1u);
    while (__hip_atomic_load(&bars[idx], __ATOMIC_RELAXED,
                             __HIP_MEMORY_SCOPE_AGENT) < (u32)GRID)
      __builtin_amdgcn_s_sleep(8);
    __threadfence();                      // acquire: invalidate stale caches
  }
  __syncthreads();
}

__global__ __launch_bounds__(256) void k_mega(
    const float* __restrict__ in0, const float* __restrict__ in1,
    u32* binMinK, u32* candCnt, float* candVal,
    u32* pCnt, double* pSum, float* segV, double* segS, int* segN,
    double* part, u32* bars, float* out) {
  __shared__ union {
    u32 lmn[NBIN];                                                   // 64 KB (B, C)
    float lv[EPB];                                                   // 4 KB  (D)
    struct { int sp[CAP]; float svv[CAP]; int dp[CAP]; float dv[CAP];
             double scv[CAP]; double dc[CAP]; } hu;                  // 64 KB (E)
    struct { float lv0[CAP]; float lv1[CAP];
             double ls0[CAP]; double ls1[CAP];
             double s0[BS]; double s1[BS]; double s2[BS]; } rm;      // 54 KB (F)
  } S;
  __shared__ int sh_ntop;
  const int blk = blockIdx.x, t = threadIdx.x;
  const int arr = blk >> 7, b = blk & 127;
  const float* pin = arr ? in1 : in0;

  // ---- phase A: init global bin mins + candidate counters ----
  {
    int i = blk * BS + t;
    if (i < 2 * NBIN) binMinK[i] = 0xFFFFFFFFu;
    if (i < 2) candCnt[i] = 0u;
  }
  gbar(bars, 0);

  // ---- phase B: exact per-bin MIN key (LDS-staged; nonempty <=> min != ~0) ----
  for (int k = t; k < NBIN; k += BS) S.lmn[k] = 0xFFFFFFFFu;
  __syncthreads();
  {
    float4 v = ((const float4*)(pin + b * EPB))[t];  // 256 x float4 = 1024 elems
    float xs[4] = {v.x, v.y, v.z, v.w};
#pragma unroll
    for (int e = 0; e < 4; e++) {
      u32 k = kasc(xs[e]);
      atomicMin(&S.lmn[k >> BSH], k);   // LDS atomics: order-independent
    }
  }
  __syncthreads();
  {
    u32* bmn = binMinK + arr * NBIN;
    for (int k = t; k < NBIN; k += BS) {
      u32 mn = S.lmn[k];
      if (mn != 0xFFFFFFFFu) atomicMin(&bmn[k], mn);  // flush nonempty only
    }
  }
  gbar(bars, 1);

  // ---- phase C: candidate detection (bin table staged back into LDS) ----
  // Flag x unless we can PROVE an element exists in (x, x+GMARG] (then the
  // sorted gap above x's run is < reg -> x cannot be a hull vertex; rigorous:
  // vertex at p => y_{p-1} > y_p => gap > reg). Proof source: first nonempty
  // higher bin's exact min (any key in a higher bin is strictly > x). Dense
  // regions always prove (next-bin min within 2*binwidth <= 0.0625 < GMARG);
  // sparse tails over-include, and the exact f64 hull discards non-vertices.
  {
    const uint4* g4 = (const uint4*)(binMinK + arr * NBIN);
    for (int k = t; k < NBIN / 4; k += BS) ((uint4*)S.lmn)[k] = g4[k];
    __syncthreads();
    if (b == 0 && t == 0) {  // right-endpoint sentinel: p = N (counts everything)
      u32 s = atomicAdd(&candCnt[arr], 1u);
      if (s < CAP) candVal[arr * CAP + s] = -INFINITY;
    }
    float4 v4 = ((const float4*)(pin + b * EPB))[t];
    float xs[4] = {v4.x, v4.y, v4.z, v4.w};
    for (int e = 0; e < 4; e++) {
      float x = xs[e];
      double xd = (double)x;
      u32 bn = kasc(x) >> BSH;
      bool proven = false;
      for (int it = 0; it < SCAN_CAP; it++) {
        bn++;
        if (bn >= NBIN) break;                    // nothing above -> flag (max elem)
        double lb = (double)kasc2f(bn << BSH);    // bin lower-boundary value
        if (lb > xd + GMARG) break;               // all further mins > x+G -> flag
        u32 mn = S.lmn[bn];
        if (mn != 0xFFFFFFFFu) {
          proven = ((double)kasc2f(mn) - xd <= GMARG);
          break;
        }
      }
      if (!proven) {
        u32 s = atomicAdd(&candCnt[arr], 1u);
        if (s < CAP) candVal[arr * CAP + s] = x;
      }
    }
  }
  gbar(bars, 2);

  // ---- phase D: per-block masked count/sum per candidate threshold ----
  // count_j = #{x > v_j}, sum_j = sum{x > v_j}; fixed shuffle tree.
  {
    ((float4*)S.lv)[t] = ((const float4*)(pin + b * EPB))[t];
    __syncthreads();
    int lane = t & 63, w = t >> 6;
    u32 cc = candCnt[arr];
    int cnt = (int)(cc < (u32)CAP ? cc : (u32)CAP);
    for (int j = w; j < cnt; j += 4) {
      float v = candVal[arr * CAP + j];
      int c = 0;
      double s = 0.0;
      for (int e = lane; e < EPB; e += 64) {
        float x = S.lv[e];
        if (x > v) { c++; s += (double)x; }
      }
#pragma unroll
      for (int o = 32; o > 0; o >>= 1) {
        c += __shfl_down(c, o);
        s += __shfl_down(s, o);
      }
      if (lane == 0) {
        pCnt[((size_t)(arr * NBA + b)) * CAP + j] = (u32)c;
        pSum[((size_t)(arr * NBA + b)) * CAP + j] = s;
      }
    }
  }
  gbar(bars, 3);

  // ---- phase E: reduce partials -> (p, C[p]); sort by p; monotone chain ----
  if (blk < 2) {
    int a2 = blk;
    u32 cc = candCnt[a2];
    int cnt = (int)(cc < (u32)CAP ? cc : (u32)CAP);
    for (int j = t; j < cnt; j += BS) {
      long long c = 0;
      double s = 0.0;
      for (int bb = 0; bb < NBA; bb++) {  // fixed order -> deterministic
        c += (long long)pCnt[((size_t)(a2 * NBA + bb)) * CAP + j];
        s += pSum[((size_t)(a2 * NBA + bb)) * CAP + j];
      }
      double pd = (double)c;
      // C[p] = S_p/reg - (p*n - p(p-1)/2), exact in f64
      S.hu.sp[j] = (int)c;
      S.hu.scv[j] = s / 0.1 - (pd * (double)N_ELEM - pd * (pd - 1.0) * 0.5);
      S.hu.svv[j] = candVal[a2 * CAP + j];
    }
    __syncthreads();
    // rank sort by (p, slot); equal-p records have identical (p,C) and the kept
    // value provably cannot change any ELEMENT's segment classification
    for (int j = t; j < cnt; j += BS) {
      int pj = S.hu.sp[j], rk = 0;
      for (int k = 0; k < cnt; k++) {
        int pk = S.hu.sp[k];
        rk += (pk < pj) || (pk == pj && k < j);
      }
      S.hu.dp[rk] = pj; S.hu.dc[rk] = S.hu.scv[j]; S.hu.dv[rk] = S.hu.svv[j];
    }
    __syncthreads();
    if (t == 0) {
      int top = 0, aX = 0, bX = 0, prevP = -1;
      double cA = 0.0, cB = 0.0;
      for (int k = 0; k < cnt; k++) {
        int i = S.hu.dp[k];
        if (i == prevP) continue;  // dedupe identical diagram points
        prevP = i;
        double Ci = S.hu.dc[k];
        float vi = S.hu.dv[k];
        while (top >= 2) {
          double cr = (double)(bX - aX) * (Ci - cA) - (cB - cA) * (double)(i - aX);
          if (cr >= 0.0) {  // bX on/below chord aX->i : pop
            top--;
            bX = aX; cB = cA;
            if (top >= 2) { aX = S.hu.dp[top - 2]; cA = S.hu.dc[top - 2]; }
          } else break;
        }
        S.hu.dp[top] = i; S.hu.dc[top] = Ci; S.hu.dv[top] = vi;
        aX = bX; cA = cB;
        bX = i;  cB = Ci;
        top++;
      }
      sh_ntop = top;
    }
    __syncthreads();
    int top = sh_ntop;
    for (int k = t; k < top - 1; k += BS) {
      segV[a2 * CAP + k] = S.hu.dv[k];  // left-vertex value (descending)
      segS[a2 * CAP + k] = (S.hu.dc[k + 1] - S.hu.dc[k]) / (double)(S.hu.dp[k + 1] - S.hu.dp[k]);
    }
    if (t == 0) segN[a2] = top - 1;
  }
  gbar(bars, 4);

  // ---- phase F: fused rank + centered moments ----
  // x in segment k iff v_k >= x > v_{k+1}; rank = x/reg - slope_k. Mean is
  // analytic: permutahedron projection preserves sum -> mean = (N+1)/2.
  {
    int n0 = segN[0], n1 = segN[1];
    for (int k = t; k < n0; k += BS) { S.rm.lv0[k] = segV[k]; S.rm.ls0[k] = segS[k]; }
    for (int k = t; k < n1; k += BS) { S.rm.lv1[k] = segV[CAP + k]; S.rm.ls1[k] = segS[CAP + k]; }
    __syncthreads();
    const double m = 0.5 * (double)(N_ELEM + 1);  // 65536.5
    double a0 = 0.0, a1 = 0.0, a2 = 0.0;
    float2 x2 = ((const float2*)(in0 + blk * 512))[t];
    float2 y2 = ((const float2*)(in1 + blk * 512))[t];
    float xs[2] = {x2.x, x2.y};
    float ys[2] = {y2.x, y2.y};
#pragma unroll
    for (int e = 0; e < 2; e++) {
      float x = xs[e], y = ys[e];
      int k0 = 0, k1 = 0;
      for (int k = 1; k < n0; k++) if (x <= S.rm.lv0[k]) k0 = k;
      for (int k = 1; k < n1; k++) if (y <= S.rm.lv1[k]) k1 = k;
      double ra = (double)x / 0.1 - S.rm.ls0[k0] - m;
      double rb = (double)y / 0.1 - S.rm.ls1[k1] - m;
      a0 += ra * rb;
      a1 += ra * ra;
      a2 += rb * rb;
    }
    S.rm.s0[t] = a0; S.rm.s1[t] = a1; S.rm.s2[t] = a2;
    __syncthreads();
    for (int off = 128; off > 0; off >>= 1) {
      if (t < off) {
        S.rm.s0[t] += S.rm.s0[t + off];
        S.rm.s1[t] += S.rm.s1[t + off];
        S.rm.s2[t] += S.rm.s2[t + off];
      }
      __syncthreads();
    }
    if (t == 0) {
      part[blk] = S.rm.s0[0];
      part[GRID + blk] = S.rm.s1[0];
      part[2 * GRID + blk] = S.rm.s2[0];
    }
  }
  gbar(bars, 5);

  // ---- phase G: final reduction (one wave, fixed tree) ----
  if (blk == 0 && t < 64) {
    double v0 = 0.0, v1 = 0.0, v2 = 0.0;
    for (int k = t; k < GRID; k += 64) {
      v0 += part[k];
      v1 += part[GRID + k];
      v2 += part[2 * GRID + k];
    }
#pragma unroll
    for (int off = 32; off > 0; off >>= 1) {
      v0 += __shfl_down(v0, off);
      v1 += __shfl_down(v1, off);
      v2 += __shfl_down(v2, off);
    }
    if (t == 0) out[0] = (float)(v0 / (sqrt(v1) * sqrt(v2)));
  }
}

// ---------------- host ----------------
extern "C" void kernel_launch(void* const* d_in, const int* in_sizes, int n_in,
                              void* d_out, int out_size, void* d_ws, size_t ws_size,
                              hipStream_t stream) {
  const float* in0 = (const float*)d_in[0];
  const float* in1 = (const float*)d_in[1];
  float* out = (float*)d_out;

  size_t off = 0;
  char* base = (char*)d_ws;
  auto alloc = [&](size_t bytes) -> char* {
    char* p = base + off;
    off += (bytes + 63) & ~(size_t)63;
    return p;
  };
  u32* binMinK = (u32*)alloc(sizeof(u32) * 2 * NBIN);
  u32* candCnt = (u32*)alloc(sizeof(u32) * 2);
  float* candVal = (float*)alloc(sizeof(float) * 2 * CAP);
  u32* pCnt    = (u32*)alloc(sizeof(u32) * 2 * NBA * CAP);
  double* pSum = (double*)alloc(sizeof(double) * 2 * NBA * CAP);
  float* segV  = (float*)alloc(sizeof(float) * 2 * CAP);
  double* segS = (double*)alloc(sizeof(double) * 2 * CAP);
  int* segN    = (int*)alloc(sizeof(int) * 2);
  double* part = (double*)alloc(sizeof(double) * 3 * GRID);
  u32* bars    = (u32*)alloc(sizeof(u32) * 16);
  (void)ws_size; (void)in_sizes; (void)n_in; (void)out_size;

  // zero the barrier counters (replayed in the graph every iteration)
  hipMemsetAsync(bars, 0, sizeof(u32) * 16, stream);

  k_mega<<<dim3(GRID), dim3(256), 0, stream>>>(
      in0, in1, binMinK, candCnt, candVal,
      pCnt, pSum, segV, segS, segN, part, bars, out);
}

// Round 10
// 67.450 us; speedup vs baseline: 2.1842x; 2.1554x over previous
//
#include <hip/hip_runtime.h>
#include <math.h>

typedef unsigned int u32;
typedef unsigned long long u64;

#define N_ELEM 131072
#define NBIN 16384         // 14-bit key-space bins (min-key only)
#define BSH 18             // key >> 18 -> bin
#define CAP 2048           // candidate capacity per array (typ. ~300 used)
#define SCAN_CAP 64        // max bins scanned upward in successor proof
#define GMARG 0.0999       // conservative gap margin (< 0.1*(1-1e-9))
#define GRID 128           // persistent blocks (66 KB LDS -> 1/CU, 128 <= 256 CUs)
#define BS 512             // threads per block (8 waves)
#define NBA 64             // data blocks per array
#define EPB 2048           // elements per block in data phases
#define NGRP 8             // barrier tree groups (16 blocks each)

// ---- coherent-point accessors (bypass non-coherent per-XCD L2) ----
__device__ __forceinline__ u32 cldu(const u32* p) {
  return __hip_atomic_load(p, __ATOMIC_RELAXED, __HIP_MEMORY_SCOPE_AGENT);
}
__device__ __forceinline__ void cstu(u32* p, u32 v) {
  __hip_atomic_store(p, v, __ATOMIC_RELAXED, __HIP_MEMORY_SCOPE_AGENT);
}
__device__ __forceinline__ int cldi(const int* p) {
  return __hip_atomic_load(p, __ATOMIC_RELAXED, __HIP_MEMORY_SCOPE_AGENT);
}
__device__ __forceinline__ void csti(int* p, int v) {
  __hip_atomic_store(p, v, __ATOMIC_RELAXED, __HIP_MEMORY_SCOPE_AGENT);
}
__device__ __forceinline__ float cldf(const float* p) {
  return __hip_atomic_load(p, __ATOMIC_RELAXED, __HIP_MEMORY_SCOPE_AGENT);
}
__device__ __forceinline__ void cstf(float* p, float v) {
  __hip_atomic_store(p, v, __ATOMIC_RELAXED, __HIP_MEMORY_SCOPE_AGENT);
}
__device__ __forceinline__ double cldd(const double* p) {
  return __hip_atomic_load(p, __ATOMIC_RELAXED, __HIP_MEMORY_SCOPE_AGENT);
}
__device__ __forceinline__ void cstd(double* p, double v) {
  __hip_atomic_store(p, v, __ATOMIC_RELAXED, __HIP_MEMORY_SCOPE_AGENT);
}

// ascending-sortable key: monotone bijection f32 -> u32
__device__ __forceinline__ u32 kasc(float x) {
  u32 u = __float_as_uint(x);
  return (u & 0x80000000u) ? ~u : (u | 0x80000000u);
}
__device__ __forceinline__ float kasc2f(u32 t) {
  return __uint_as_float((t & 0x80000000u) ? (t ^ 0x80000000u) : ~t);
}

// Fenceless device-scope tree barrier. Correctness: all cross-phase data goes
// through coherent-point ops (cst*/cld*/atomics); __syncthreads drains every
// wave's vmcnt (compiler emits s_waitcnt before s_barrier) so all the block's
// coherent stores are globally visible before the leader's arrival RMW.
// No __threadfence -> no per-XCD L2 writeback/invalidate storms.
__device__ __forceinline__ void gbar(u32* bar, int idx) {
  __syncthreads();
  if (threadIdx.x == 0) {
    int g = (int)(blockIdx.x >> 4);  // 8 groups x 16 blocks
    u32 old = __hip_atomic_fetch_add(&bar[(idx * NGRP + g) * 32], 1u,
                                     __ATOMIC_RELAXED, __HIP_MEMORY_SCOPE_AGENT);
    if (old == 15u)
      __hip_atomic_fetch_add(&bar[(5 * NGRP + idx) * 32], 1u,
                             __ATOMIC_RELAXED, __HIP_MEMORY_SCOPE_AGENT);
    while (__hip_atomic_load(&bar[(5 * NGRP + idx) * 32], __ATOMIC_RELAXED,
                             __HIP_MEMORY_SCOPE_AGENT) < (u32)NGRP)
      __builtin_amdgcn_s_sleep(1);
  }
  __syncthreads();
}
// bar layout (u32 units, all zeroed by hipMemsetAsync each call):
//   [0 .. 5*8*32)           group counters (5 barriers x 8 groups, 128B apart)
//   [(40+idx)*32]           root counters (5)
//   [CC0_OFF], [CC1_OFF]    candidate counters per array
//   [DONE_OFF]              last-block-out counter
#define CC_OFF   (48 * 32)
#define DONE_OFF (50 * 32)
#define BAR_U32  (51 * 32)

__global__ __launch_bounds__(BS) void k_mega(
    const float* __restrict__ in0, const float* __restrict__ in1,
    u32* binMinK, float* candVal, u32* pCnt, double* pSum,
    float* segV, double* segS, int* segN, double* part,
    u32* bar, float* out) {
  __shared__ union {
    u32 lmn[NBIN];                                                   // 64 KB (B, C)
    float lv[EPB];                                                   // 8 KB  (D)
    struct { int sp[CAP]; float svv[CAP]; int dp[CAP]; float dv[CAP];
             double scv[CAP]; double dc[CAP]; } hu;                  // 64 KB (E)
    struct { float lv0[CAP]; float lv1[CAP];
             double ls0[CAP]; double ls1[CAP];
             double s0[BS]; double s1[BS]; double s2[BS]; } rm;      // 60 KB (F)
  } S;
  __shared__ int sh_ntop;
  __shared__ int sh_last;
  const int blk = blockIdx.x, t = threadIdx.x;
  const int arr = blk >> 6, b = blk & 63;
  const float* pin = arr ? in1 : in0;
  u32* candCnt = bar + CC_OFF;  // candCnt[arr*32]

  // ---- phase A: init global bin mins (coherent stores; table is read via
  // coherent loads and updated via atomicMin -> must live at coherent point) ----
  {
    int i = blk * BS + t;  // 128*512 = 65536 >= 32768
    if (i < 2 * NBIN) cstu(&binMinK[i], 0xFFFFFFFFu);
  }
  gbar(bar, 0);

  // ---- phase B: exact per-bin MIN key (LDS-staged; nonempty <=> min != ~0) ----
  for (int k = t; k < NBIN; k += BS) S.lmn[k] = 0xFFFFFFFFu;
  __syncthreads();
  {
    float4 v = ((const float4*)(pin + b * EPB))[t];  // 512 x float4 = 2048
    float xs[4] = {v.x, v.y, v.z, v.w};
#pragma unroll
    for (int e = 0; e < 4; e++) {
      u32 k = kasc(xs[e]);
      atomicMin(&S.lmn[k >> BSH], k);   // LDS atomics: order-independent
    }
  }
  __syncthreads();
  {
    u32* bmn = binMinK + arr * NBIN;
    for (int k = t; k < NBIN; k += BS) {
      u32 mn = S.lmn[k];
      if (mn != 0xFFFFFFFFu) atomicMin(&bmn[k], mn);  // coherent RMW merge
    }
  }
  gbar(bar, 1);

  // ---- phase C: candidate detection (bin table staged into LDS) ----
  // Flag x unless we can PROVE an element exists in (x, x+GMARG] (then the
  // sorted gap above x's run is < reg -> x cannot be a hull vertex; rigorous:
  // vertex at p => y_{p-1} > y_p => gap > reg). Proof source: first nonempty
  // higher bin's exact min. Dense regions always prove; sparse tails
  // over-include, and the exact f64 hull (phase E) discards non-vertices.
  {
    const u32* bmn = binMinK + arr * NBIN;
    for (int k = t; k < NBIN; k += BS) S.lmn[k] = cldu(&bmn[k]);
    __syncthreads();
    if (blk == 0 && t == 0) {  // right-endpoint sentinel: p = N
      u32 s = atomicAdd(&candCnt[0], 1u);
      if (s < CAP) cstf(&candVal[s], -INFINITY);
    }
    if (blk == (1 << 6) && t == 0) {
      u32 s = atomicAdd(&candCnt[32], 1u);
      if (s < CAP) cstf(&candVal[CAP + s], -INFINITY);
    }
    float4 v4 = ((const float4*)(pin + b * EPB))[t];
    float xs[4] = {v4.x, v4.y, v4.z, v4.w};
    for (int e = 0; e < 4; e++) {
      float x = xs[e];
      double xd = (double)x;
      u32 bn = kasc(x) >> BSH;
      bool proven = false;
      for (int it = 0; it < SCAN_CAP; it++) {
        bn++;
        if (bn >= NBIN) break;                    // nothing above -> flag
        double lb = (double)kasc2f(bn << BSH);    // bin lower-boundary value
        if (lb > xd + GMARG) break;               // all further mins > x+G -> flag
        u32 mn = S.lmn[bn];
        if (mn != 0xFFFFFFFFu) {
          proven = ((double)kasc2f(mn) - xd <= GMARG);
          break;
        }
      }
      if (!proven) {
        u32 s = atomicAdd(&candCnt[arr * 32], 1u);
        if (s < CAP) cstf(&candVal[arr * CAP + s], x);
      }
    }
  }
  gbar(bar, 2);

  // ---- phase D: per-block masked count/sum per candidate threshold ----
  // count_j = #{x > v_j}, sum_j = sum{x > v_j}; fixed shuffle tree.
  // Layout pCnt/pSum[(arr*CAP + j)*NBA + b] -> phase E reads contiguous.
  {
    ((float4*)S.lv)[t] = ((const float4*)(pin + b * EPB))[t];
    __syncthreads();
    int lane = t & 63, w = t >> 6;  // 8 waves
    u32 cc = cldu(&candCnt[arr * 32]);
    int cnt = (int)(cc < (u32)CAP ? cc : (u32)CAP);
    for (int j = w; j < cnt; j += 8) {
      float v = cldf(&candVal[arr * CAP + j]);
      int c0 = 0, c1 = 0;
      double s0 = 0.0, s1 = 0.0;
      for (int e = lane; e < EPB / 2; e += 64) {  // 16 iters, 2 indep chains
        float x = S.lv[e];
        float y = S.lv[e + EPB / 2];
        if (x > v) { c0++; s0 += (double)x; }
        if (y > v) { c1++; s1 += (double)y; }
      }
      int c = c0 + c1;
      double s = s0 + s1;
#pragma unroll
      for (int o = 32; o > 0; o >>= 1) {
        c += __shfl_down(c, o);
        s += __shfl_down(s, o);
      }
      if (lane == 0) {
        cstu(&pCnt[((size_t)(arr * CAP + j)) * NBA + b], (u32)c);
        cstd(&pSum[((size_t)(arr * CAP + j)) * NBA + b], s);
      }
    }
  }
  gbar(bar, 3);

  // ---- phase E: reduce partials -> (p, C[p]); sort by p; monotone chain ----
  if (blk < 2) {
    int a2 = blk;
    u32 cc = cldu(&candCnt[a2 * 32]);
    int cnt = (int)(cc < (u32)CAP ? cc : (u32)CAP);
    for (int j = t; j < cnt; j += BS) {
      const u32* pc = &pCnt[((size_t)(a2 * CAP + j)) * NBA];
      const double* ps = &pSum[((size_t)(a2 * CAP + j)) * NBA];
      long long c = 0;
      double s0 = 0.0, s1 = 0.0, s2 = 0.0, s3 = 0.0;
      u32 c0 = 0, c1 = 0, c2 = 0, c3 = 0;
#pragma unroll
      for (int bb = 0; bb < NBA; bb += 4) {  // 4 indep chains for MLP
        c0 += cldu(&pc[bb]);     s0 += cldd(&ps[bb]);
        c1 += cldu(&pc[bb + 1]); s1 += cldd(&ps[bb + 1]);
        c2 += cldu(&pc[bb + 2]); s2 += cldd(&ps[bb + 2]);
        c3 += cldu(&pc[bb + 3]); s3 += cldd(&ps[bb + 3]);
      }
      c = (long long)c0 + c1 + c2 + c3;
      double s = ((s0 + s1) + (s2 + s3));
      double pd = (double)c;
      // C[p] = S_p/reg - (p*n - p(p-1)/2), exact in f64
      S.hu.sp[j] = (int)c;
      S.hu.scv[j] = s / 0.1 - (pd * (double)N_ELEM - pd * (pd - 1.0) * 0.5);
      S.hu.svv[j] = cldf(&candVal[a2 * CAP + j]);
    }
    __syncthreads();
    // rank sort by (p, slot); equal-p records are provably identical (distinct
    // element values have distinct p), so slot-order nondeterminism is benign
    for (int j = t; j < cnt; j += BS) {
      int pj = S.hu.sp[j], rk = 0;
      for (int k = 0; k < cnt; k++) {
        int pk = S.hu.sp[k];
        rk += (pk < pj) || (pk == pj && k < j);
      }
      S.hu.dp[rk] = pj; S.hu.dc[rk] = S.hu.scv[j]; S.hu.dv[rk] = S.hu.svv[j];
    }
    __syncthreads();
    if (t == 0) {
      int top = 0, aX = 0, bX = 0, prevP = -1;
      double cA = 0.0, cB = 0.0;
      for (int k = 0; k < cnt; k++) {
        int i = S.hu.dp[k];
        if (i == prevP) continue;  // dedupe identical diagram points
        prevP = i;
        double Ci = S.hu.dc[k];
        float vi = S.hu.dv[k];
        while (top >= 2) {
          double cr = (double)(bX - aX) * (Ci - cA) - (cB - cA) * (double)(i - aX);
          if (cr >= 0.0) {  // bX on/below chord aX->i : pop
            top--;
            bX = aX; cB = cA;
            if (top >= 2) { aX = S.hu.dp[top - 2]; cA = S.hu.dc[top - 2]; }
          } else break;
        }
        S.hu.dp[top] = i; S.hu.dc[top] = Ci; S.hu.dv[top] = vi;
        aX = bX; cA = cB;
        bX = i;  cB = Ci;
        top++;
      }
      sh_ntop = top;
    }
    __syncthreads();
    int top = sh_ntop;
    for (int k = t; k < top - 1; k += BS) {
      cstf(&segV[a2 * CAP + k], S.hu.dv[k]);  // left-vertex value (descending)
      cstd(&segS[a2 * CAP + k],
           (S.hu.dc[k + 1] - S.hu.dc[k]) / (double)(S.hu.dp[k + 1] - S.hu.dp[k]));
    }
    if (t == 0) csti(&segN[a2], top - 1);
  }
  gbar(bar, 4);

  // ---- phase F: fused rank + centered moments ----
  // x in segment k iff v_k >= x > v_{k+1}; rank = x/reg - slope_k. Mean is
  // analytic: permutahedron projection preserves sum -> mean = (N+1)/2.
  {
    int n0 = cldi(&segN[0]), n1 = cldi(&segN[1]);
    for (int k = t; k < n0; k += BS) { S.rm.lv0[k] = cldf(&segV[k]); S.rm.ls0[k] = cldd(&segS[k]); }
    for (int k = t; k < n1; k += BS) { S.rm.lv1[k] = cldf(&segV[CAP + k]); S.rm.ls1[k] = cldd(&segS[CAP + k]); }
    __syncthreads();
    const double m = 0.5 * (double)(N_ELEM + 1);  // 65536.5
    double a0 = 0.0, a1 = 0.0, a2 = 0.0;
    float2 x2 = ((const float2*)(in0 + blk * 1024))[t];
    float2 y2 = ((const float2*)(in1 + blk * 1024))[t];
    float xs[2] = {x2.x, x2.y};
    float ys[2] = {y2.x, y2.y};
#pragma unroll
    for (int e = 0; e < 2; e++) {
      float x = xs[e], y = ys[e];
      int k0 = 0, k1 = 0;
      for (int k = 1; k < n0; k++) if (x <= S.rm.lv0[k]) k0 = k;
      for (int k = 1; k < n1; k++) if (y <= S.rm.lv1[k]) k1 = k;
      double ra = (double)x / 0.1 - S.rm.ls0[k0] - m;
      double rb = (double)y / 0.1 - S.rm.ls1[k1] - m;
      a0 += ra * rb;
      a1 += ra * ra;
      a2 += rb * rb;
    }
    S.rm.s0[t] = a0; S.rm.s1[t] = a1; S.rm.s2[t] = a2;
    __syncthreads();
    for (int off = BS / 2; off > 0; off >>= 1) {
      if (t < off) {
        S.rm.s0[t] += S.rm.s0[t + off];
        S.rm.s1[t] += S.rm.s1[t + off];
        S.rm.s2[t] += S.rm.s2[t + off];
      }
      __syncthreads();
    }
    if (t == 0) {
      cstd(&part[blk], S.rm.s0[0]);
      cstd(&part[GRID + blk], S.rm.s1[0]);
      cstd(&part[2 * GRID + blk], S.rm.s2[0]);
    }
  }

  // ---- phase G: last-block-out final reduction (no 6th barrier) ----
  __syncthreads();  // drains t0's part stores (compiler waits vmcnt pre-barrier)
  if (t == 0) {
    u32 old = __hip_atomic_fetch_add(&bar[DONE_OFF], 1u,
                                     __ATOMIC_RELAXED, __HIP_MEMORY_SCOPE_AGENT);
    sh_last = (old == (u32)(GRID - 1)) ? 1 : 0;
  }
  __syncthreads();
  if (sh_last && t < 64) {
    double v0 = 0.0, v1 = 0.0, v2 = 0.0;
    for (int k = t; k < GRID; k += 64) {  // fixed order -> deterministic
      v0 += cldd(&part[k]);
      v1 += cldd(&part[GRID + k]);
      v2 += cldd(&part[2 * GRID + k]);
    }
#pragma unroll
    for (int off = 32; off > 0; off >>= 1) {
      v0 += __shfl_down(v0, off);
      v1 += __shfl_down(v1, off);
      v2 += __shfl_down(v2, off);
    }
    if (t == 0) out[0] = (float)(v0 / (sqrt(v1) * sqrt(v2)));
  }
}

// ---------------- host ----------------
extern "C" void kernel_launch(void* const* d_in, const int* in_sizes, int n_in,
                              void* d_out, int out_size, void* d_ws, size_t ws_size,
                              hipStream_t stream) {
  const float* in0 = (const float*)d_in[0];
  const float* in1 = (const float*)d_in[1];
  float* out = (float*)d_out;

  size_t off = 0;
  char* base = (char*)d_ws;
  auto alloc = [&](size_t bytes) -> char* {
    char* p = base + off;
    off += (bytes + 63) & ~(size_t)63;
    return p;
  };
  u32* binMinK = (u32*)alloc(sizeof(u32) * 2 * NBIN);
  float* candVal = (float*)alloc(sizeof(float) * 2 * CAP);
  u32* pCnt    = (u32*)alloc(sizeof(u32) * 2 * CAP * NBA);
  double* pSum = (double*)alloc(sizeof(double) * 2 * CAP * NBA);
  float* segV  = (float*)alloc(sizeof(float) * 2 * CAP);
  double* segS = (double*)alloc(sizeof(double) * 2 * CAP);
  int* segN    = (int*)alloc(sizeof(int) * 2);
  double* part = (double*)alloc(sizeof(double) * 3 * GRID);
  u32* bar     = (u32*)alloc(sizeof(u32) * BAR_U32);
  (void)ws_size; (void)in_sizes; (void)n_in; (void)out_size;

  // zero barrier tree + candidate counters + done counter (replayed in graph)
  hipMemsetAsync(bar, 0, sizeof(u32) * BAR_U32, stream);

  k_mega<<<dim3(GRID), dim3(BS), 0, stream>>>(
      in0, in1, binMinK, candVal, pCnt, pSum, segV, segS, segN, part, bar, out);
}

// Round 11
// 59.831 us; speedup vs baseline: 2.4623x; 1.1273x over previous
//
#include <hip/hip_runtime.h>
#include <math.h>

typedef unsigned int u32;
typedef unsigned long long u64;

#define N_ELEM 131072
#define NBIN 16384         // 14-bit key-space bins (min-key only)
#define BSH 18             // key >> 18 -> bin
#define CAP 2048           // candidate capacity per array (typ. ~400 used)
#define SCAN_CAP 64        // max bins scanned upward in successor proof
#define GMARG 0.0999       // conservative gap margin (< 0.1*(1-1e-9))
#define GRID 128           // persistent blocks (<= 256 CUs -> co-resident)
#define BS 512             // threads per block (8 waves)
#define NBA 64             // data blocks per array
#define EPB 2048           // elements per block in data phases
#define NGRP 8             // barrier tree groups (16 blocks each)
#define SCALE 1099511627776.0  // 2^40 fixed-point scale for exact i64 sums

// ---- coherent-point accessors (bypass non-coherent per-XCD L2) ----
__device__ __forceinline__ u32 cldu(const u32* p) {
  return __hip_atomic_load(p, __ATOMIC_RELAXED, __HIP_MEMORY_SCOPE_AGENT);
}
__device__ __forceinline__ void cstu(u32* p, u32 v) {
  __hip_atomic_store(p, v, __ATOMIC_RELAXED, __HIP_MEMORY_SCOPE_AGENT);
}
__device__ __forceinline__ u64 cldull(const u64* p) {
  return __hip_atomic_load(p, __ATOMIC_RELAXED, __HIP_MEMORY_SCOPE_AGENT);
}
__device__ __forceinline__ void cstull(u64* p, u64 v) {
  __hip_atomic_store(p, v, __ATOMIC_RELAXED, __HIP_MEMORY_SCOPE_AGENT);
}
__device__ __forceinline__ int cldi(const int* p) {
  return __hip_atomic_load(p, __ATOMIC_RELAXED, __HIP_MEMORY_SCOPE_AGENT);
}
__device__ __forceinline__ void csti(int* p, int v) {
  __hip_atomic_store(p, v, __ATOMIC_RELAXED, __HIP_MEMORY_SCOPE_AGENT);
}
__device__ __forceinline__ float cldf(const float* p) {
  return __hip_atomic_load(p, __ATOMIC_RELAXED, __HIP_MEMORY_SCOPE_AGENT);
}
__device__ __forceinline__ void cstf(float* p, float v) {
  __hip_atomic_store(p, v, __ATOMIC_RELAXED, __HIP_MEMORY_SCOPE_AGENT);
}
__device__ __forceinline__ double cldd(const double* p) {
  return __hip_atomic_load(p, __ATOMIC_RELAXED, __HIP_MEMORY_SCOPE_AGENT);
}
__device__ __forceinline__ void cstd(double* p, double v) {
  __hip_atomic_store(p, v, __ATOMIC_RELAXED, __HIP_MEMORY_SCOPE_AGENT);
}

// ascending-sortable key: monotone bijection f32 -> u32
__device__ __forceinline__ u32 kasc(float x) {
  u32 u = __float_as_uint(x);
  return (u & 0x80000000u) ? ~u : (u | 0x80000000u);
}
__device__ __forceinline__ float kasc2f(u32 t) {
  return __uint_as_float((t & 0x80000000u) ? (t ^ 0x80000000u) : ~t);
}

// Fenceless device-scope tree barrier (proven r10). All cross-phase data goes
// through coherent-point ops; __syncthreads drains each wave's vmcnt before
// s_barrier, so the block's coherent stores are globally visible before the
// leader's arrival RMW. No __threadfence -> no L2 writeback/invalidate storms.
__device__ __forceinline__ void gbar(u32* bar, int idx) {
  __syncthreads();
  if (threadIdx.x == 0) {
    int g = (int)(blockIdx.x >> 4);  // 8 groups x 16 blocks
    u32 old = __hip_atomic_fetch_add(&bar[(idx * NGRP + g) * 32], 1u,
                                     __ATOMIC_RELAXED, __HIP_MEMORY_SCOPE_AGENT);
    if (old == 15u)
      __hip_atomic_fetch_add(&bar[(4 * NGRP + idx) * 32], 1u,
                             __ATOMIC_RELAXED, __HIP_MEMORY_SCOPE_AGENT);
    while (__hip_atomic_load(&bar[(4 * NGRP + idx) * 32], __ATOMIC_RELAXED,
                             __HIP_MEMORY_SCOPE_AGENT) < (u32)NGRP)
      __builtin_amdgcn_s_sleep(1);
  }
  __syncthreads();
}
// bar layout (u32, zeroed by hipMemsetAsync each call): group counters
// (4 barriers x 8 groups, 128 B apart), roots, candidate counters, done.
#define CC_OFF   (40 * 32)
#define DONE_OFF (42 * 32)
#define BAR_U32  (43 * 32)

__global__ __launch_bounds__(BS) void k_mega(
    const float* __restrict__ in0, const float* __restrict__ in1,
    u32* binMinK, float* candVal, u32* pCnt, u64* pSum,
    float* segV, double* segS, int* segN, double* part,
    u32* bar, float* out) {
  __shared__ union {
    u32 lmn[NBIN];                                                   // 64 KB (B)
    struct { float raw[CAP]; float sv[CAP];
             u32 sc[CAP]; u64 ss[CAP]; } d;                          // 40 KB (D)
    struct { float raw[CAP]; float v[CAP];
             u32 h[CAP]; u64 hs[CAP];
             u64 ts[BS]; u32 tc[BS]; } e;                            // 46 KB (E)
    struct { float lv0[CAP]; float lv1[CAP];
             double ls0[CAP]; double ls1[CAP];
             double s0[BS]; double s1[BS]; double s2[BS]; } f;       // 60 KB (F)
  } S;
  __shared__ int sh_ntop;
  __shared__ int sh_last;
  const int blk = blockIdx.x, t = threadIdx.x;
  const int arr = blk >> 6, b = blk & 63;
  const float* pin = arr ? in1 : in0;
  u32* candCnt = bar + CC_OFF;  // candCnt[arr*32]

  // ---- phase B: exact per-bin MIN key (LDS-staged; nonempty <=> min != ~0).
  // binMinK pre-initialized to 0xFFFFFFFF by host hipMemsetAsync(0xFF). ----
  for (int k = t; k < NBIN; k += BS) S.lmn[k] = 0xFFFFFFFFu;
  __syncthreads();
  {
    float4 v = ((const float4*)(pin + b * EPB))[t];  // 512 x float4 = 2048
    float xs[4] = {v.x, v.y, v.z, v.w};
#pragma unroll
    for (int e = 0; e < 4; e++) {
      u32 k = kasc(xs[e]);
      atomicMin(&S.lmn[k >> BSH], k);   // LDS atomics: order-independent
    }
  }
  __syncthreads();
  {
    u32* bmn = binMinK + arr * NBIN;
    for (int k = t; k < NBIN; k += BS) {
      u32 mn = S.lmn[k];
      if (mn != 0xFFFFFFFFu) atomicMin(&bmn[k], mn);  // coherent RMW merge
    }
  }
  gbar(bar, 0);

  // ---- phase C: candidate detection (direct coherent reads of bin table) ----
  // Flag x unless we can PROVE an element exists in (x, x+GMARG] (then the
  // sorted gap above x's run is < reg -> x cannot be a hull vertex; rigorous:
  // vertex at p => y_{p-1} > y_p => gap > reg). Proof source: first nonempty
  // higher bin's exact min. Over-inclusion safe: every flagged v yields a
  // valid diagram point (p, C[p]); the exact f64 hull discards non-vertices.
  {
    const u32* bmn = binMinK + arr * NBIN;
    if ((blk == 0 || blk == 64) && t == 0) {  // right-endpoint sentinel: p = N
      u32 s = atomicAdd(&candCnt[arr * 32], 1u);
      if (s < CAP) cstf(&candVal[arr * CAP + s], -INFINITY);
    }
    float4 v4 = ((const float4*)(pin + b * EPB))[t];
    float xs[4] = {v4.x, v4.y, v4.z, v4.w};
    for (int e = 0; e < 4; e++) {
      float x = xs[e];
      double xd = (double)x;
      u32 bn = kasc(x) >> BSH;
      bool proven = false;
      for (int it = 0; it < SCAN_CAP; it++) {
        bn++;
        if (bn >= NBIN) break;                    // nothing above -> flag
        double lb = (double)kasc2f(bn << BSH);    // bin lower-boundary value
        if (lb > xd + GMARG) break;               // all further mins > x+G -> flag
        u32 mn = cldu(&bmn[bn]);
        if (mn != 0xFFFFFFFFu) {
          proven = ((double)kasc2f(mn) - xd <= GMARG);
          break;
        }
      }
      if (!proven) {
        u32 s = atomicAdd(&candCnt[arr * 32], 1u);
        if (s < CAP) cstf(&candVal[arr * CAP + s], x);
      }
    }
  }
  gbar(bar, 1);

  // ---- phase D: segment histogram per block ----
  // Thresholds sorted descending (redundant per block, deterministic: equal
  // values produce identical sorted content). Element -> segment s(x) =
  // #{v >= x} by binary search; per-segment count (u32) and exact fixed-point
  // sum (i64, llrint(x*2^40) -- order-independent, deterministic).
  int cnt;
  {
    u32 cc = cldu(&candCnt[arr * 32]);
    cnt = (int)(cc < (u32)CAP ? cc : (u32)CAP);
    for (int j = t; j < cnt; j += BS) S.d.raw[j] = cldf(&candVal[arr * CAP + j]);
    __syncthreads();
    for (int j = t; j < cnt; j += BS) {
      float vj = S.d.raw[j];
      int rk = 0;
      for (int k = 0; k < cnt; k++) {
        float vk = S.d.raw[k];
        rk += (vk > vj) || (vk == vj && k < j);
      }
      S.d.sv[rk] = vj;
    }
    for (int j = t; j < cnt; j += BS) { S.d.sc[j] = 0u; S.d.ss[j] = 0ull; }
    __syncthreads();
    float4 v4 = ((const float4*)(pin + b * EPB))[t];
    float xs[4] = {v4.x, v4.y, v4.z, v4.w};
#pragma unroll
    for (int e = 0; e < 4; e++) {
      float x = xs[e];
      int lo = 0, hi = cnt;
      while (lo < hi) {  // descending array: prefix [0,lo) >= x
        int mid = (lo + hi) >> 1;
        if (S.d.sv[mid] >= x) lo = mid + 1; else hi = mid;
      }
      atomicAdd(&S.d.sc[lo], 1u);
      atomicAdd(&S.d.ss[lo], (u64)(long long)llrint((double)x * SCALE));
    }
    __syncthreads();
    for (int j = t; j < cnt; j += BS) {
      cstu(&pCnt[((size_t)(arr * CAP + j)) * NBA + b], S.d.sc[j]);
      cstull(&pSum[((size_t)(arr * CAP + j)) * NBA + b], S.d.ss[j]);
    }
  }
  gbar(bar, 2);

  // ---- phase E: reduce partials -> prefix -> (p, C[p]) -> monotone chain ----
  // count_j = #{x > v_j} = inclusive prefix of hist through segment j
  // (x > v_j <=> s(x) <= j). (p, C) list is already sorted by p (prefix is
  // monotone); duplicate thresholds give identical (p, C) -> prevP dedupe.
  if (blk < 2) {
    int a2 = blk;
    u32 cc = cldu(&candCnt[a2 * 32]);
    int cn = (int)(cc < (u32)CAP ? cc : (u32)CAP);
    for (int j = t; j < cn; j += BS) S.e.raw[j] = cldf(&candVal[a2 * CAP + j]);
    __syncthreads();
    for (int j = t; j < cn; j += BS) {
      float vj = S.e.raw[j];
      int rk = 0;
      for (int k = 0; k < cn; k++) {
        float vk = S.e.raw[k];
        rk += (vk > vj) || (vk == vj && k < j);
      }
      S.e.v[rk] = vj;
    }
    // reduce 64 integer partials per segment (exact, any order)
    for (int j = t; j < cn; j += BS) {
      const u32* pc = &pCnt[((size_t)(a2 * CAP + j)) * NBA];
      const u64* ps = &pSum[((size_t)(a2 * CAP + j)) * NBA];
      u32 c = 0; u64 s = 0;
      for (int bb = 0; bb < NBA; bb++) { c += cldu(&pc[bb]); s += cldull(&ps[bb]); }
      S.e.h[j] = c; S.e.hs[j] = s;
    }
    __syncthreads();
    // inclusive prefix over [0, cn): 4 entries/thread + block scan (exact i64)
    {
      int base = t * 4;
      u32 rc = 0; u64 rs = 0;
#pragma unroll
      for (int i = 0; i < 4; i++) {
        int j = base + i;
        if (j < cn) {
          rc += S.e.h[j]; rs += S.e.hs[j];
          S.e.h[j] = rc;  S.e.hs[j] = rs;
        }
      }
      S.e.tc[t] = rc; S.e.ts[t] = rs;
      __syncthreads();
      for (int off = 1; off < BS; off <<= 1) {
        u32 vc = (t >= off) ? S.e.tc[t - off] : 0u;
        u64 vs = (t >= off) ? S.e.ts[t - off] : 0ull;
        __syncthreads();
        S.e.tc[t] += vc; S.e.ts[t] += vs;
        __syncthreads();
      }
      u32 ec = S.e.tc[t] - rc;  // exclusive thread offset
      u64 es = S.e.ts[t] - rs;
#pragma unroll
      for (int i = 0; i < 4; i++) {
        int j = base + i;
        if (j < cn) { S.e.h[j] += ec; S.e.hs[j] += es; }
      }
    }
    __syncthreads();
    // convert: C[p_j] = S_j/reg - (p*n - p(p-1)/2), exact-in-f64 inputs
    for (int j = t; j < cn; j += BS) {
      double pd = (double)S.e.h[j];
      double s = (double)(long long)S.e.hs[j] / SCALE;
      ((double*)S.e.hs)[j] = s / 0.1 - (pd * (double)N_ELEM - pd * (pd - 1.0) * 0.5);
    }
    __syncthreads();
    if (t == 0) {  // monotone chain, in-place stack (write idx <= read idx)
      double* Cv = (double*)S.e.hs;
      int top = 0, aX = 0, bX = 0, prevP = -1;
      double cA = 0.0, cB = 0.0;
      for (int k = 0; k < cn; k++) {
        int i = (int)S.e.h[k];
        if (i == prevP) continue;  // dedupe identical diagram points
        prevP = i;
        double Ci = Cv[k];
        float vi = S.e.v[k];
        while (top >= 2) {
          double cr = (double)(bX - aX) * (Ci - cA) - (cB - cA) * (double)(i - aX);
          if (cr >= 0.0) {  // bX on/below chord aX->i : pop
            top--;
            bX = aX; cB = cA;
            if (top >= 2) { aX = (int)S.e.h[top - 2]; cA = Cv[top - 2]; }
          } else break;
        }
        S.e.h[top] = (u32)i; Cv[top] = Ci; S.e.v[top] = vi;
        aX = bX; cA = cB;
        bX = i;  cB = Ci;
        top++;
      }
      sh_ntop = top;
    }
    __syncthreads();
    {
      double* Cv = (double*)S.e.hs;
      int top = sh_ntop;
      for (int k = t; k < top - 1; k += BS) {
        cstf(&segV[a2 * CAP + k], S.e.v[k]);  // left-vertex value (descending)
        cstd(&segS[a2 * CAP + k],
             (Cv[k + 1] - Cv[k]) / (double)((int)S.e.h[k + 1] - (int)S.e.h[k]));
      }
      if (t == 0) csti(&segN[a2], top - 1);
    }
  }
  gbar(bar, 3);

  // ---- phase F: fused rank + centered moments ----
  // x in segment k iff v_k >= x > v_{k+1}; rank = x/reg - slope_k. Mean is
  // analytic: permutahedron projection preserves sum -> mean = (N+1)/2.
  {
    int n0 = cldi(&segN[0]), n1 = cldi(&segN[1]);
    for (int k = t; k < n0; k += BS) { S.f.lv0[k] = cldf(&segV[k]); S.f.ls0[k] = cldd(&segS[k]); }
    for (int k = t; k < n1; k += BS) { S.f.lv1[k] = cldf(&segV[CAP + k]); S.f.ls1[k] = cldd(&segS[CAP + k]); }
    __syncthreads();
    const double m = 0.5 * (double)(N_ELEM + 1);  // 65536.5
    double a0 = 0.0, a1 = 0.0, a2 = 0.0;
    float2 x2 = ((const float2*)(in0 + blk * 1024))[t];
    float2 y2 = ((const float2*)(in1 + blk * 1024))[t];
    float xs[2] = {x2.x, x2.y};
    float ys[2] = {y2.x, y2.y};
#pragma unroll
    for (int e = 0; e < 2; e++) {
      float x = xs[e], y = ys[e];
      int k0 = 0, k1 = 0;
      for (int k = 1; k < n0; k++) if (x <= S.f.lv0[k]) k0 = k;
      for (int k = 1; k < n1; k++) if (y <= S.f.lv1[k]) k1 = k;
      double ra = (double)x / 0.1 - S.f.ls0[k0] - m;
      double rb = (double)y / 0.1 - S.f.ls1[k1] - m;
      a0 += ra * rb;
      a1 += ra * ra;
      a2 += rb * rb;
    }
    S.f.s0[t] = a0; S.f.s1[t] = a1; S.f.s2[t] = a2;
    __syncthreads();
    for (int off = BS / 2; off > 0; off >>= 1) {
      if (t < off) {
        S.f.s0[t] += S.f.s0[t + off];
        S.f.s1[t] += S.f.s1[t + off];
        S.f.s2[t] += S.f.s2[t + off];
      }
      __syncthreads();
    }
    if (t == 0) {
      cstd(&part[blk], S.f.s0[0]);
      cstd(&part[GRID + blk], S.f.s1[0]);
      cstd(&part[2 * GRID + blk], S.f.s2[0]);
    }
  }

  // ---- phase G: last-block-out final reduction ----
  __syncthreads();  // drains t0's part stores (vmcnt waited before s_barrier)
  if (t == 0) {
    u32 old = __hip_atomic_fetch_add(&bar[DONE_OFF], 1u,
                                     __ATOMIC_RELAXED, __HIP_MEMORY_SCOPE_AGENT);
    sh_last = (old == (u32)(GRID - 1)) ? 1 : 0;
  }
  __syncthreads();
  if (sh_last && t < 64) {
    double v0 = 0.0, v1 = 0.0, v2 = 0.0;
    for (int k = t; k < GRID; k += 64) {  // fixed order -> deterministic
      v0 += cldd(&part[k]);
      v1 += cldd(&part[GRID + k]);
      v2 += cldd(&part[2 * GRID + k]);
    }
#pragma unroll
    for (int off = 32; off > 0; off >>= 1) {
      v0 += __shfl_down(v0, off);
      v1 += __shfl_down(v1, off);
      v2 += __shfl_down(v2, off);
    }
    if (t == 0) out[0] = (float)(v0 / (sqrt(v1) * sqrt(v2)));
  }
}

// ---------------- host ----------------
extern "C" void kernel_launch(void* const* d_in, const int* in_sizes, int n_in,
                              void* d_out, int out_size, void* d_ws, size_t ws_size,
                              hipStream_t stream) {
  const float* in0 = (const float*)d_in[0];
  const float* in1 = (const float*)d_in[1];
  float* out = (float*)d_out;

  size_t off = 0;
  char* base = (char*)d_ws;
  auto alloc = [&](size_t bytes) -> char* {
    char* p = base + off;
    off += (bytes + 63) & ~(size_t)63;
    return p;
  };
  u32* binMinK = (u32*)alloc(sizeof(u32) * 2 * NBIN);
  float* candVal = (float*)alloc(sizeof(float) * 2 * CAP);
  u32* pCnt    = (u32*)alloc(sizeof(u32) * 2 * CAP * NBA);
  u64* pSum    = (u64*)alloc(sizeof(u64) * 2 * CAP * NBA);
  float* segV  = (float*)alloc(sizeof(float) * 2 * CAP);
  double* segS = (double*)alloc(sizeof(double) * 2 * CAP);
  int* segN    = (int*)alloc(sizeof(int) * 2);
  double* part = (double*)alloc(sizeof(double) * 3 * GRID);
  u32* bar     = (u32*)alloc(sizeof(u32) * BAR_U32);
  (void)ws_size; (void)in_sizes; (void)n_in; (void)out_size;

  // init: bin mins to 0xFFFFFFFF (0xFF bytes), barrier/counters to 0.
  // Both replayed inside the graph every iteration -> stateless.
  hipMemsetAsync(binMinK, 0xFF, sizeof(u32) * 2 * NBIN, stream);
  hipMemsetAsync(bar, 0, sizeof(u32) * BAR_U32, stream);

  k_mega<<<dim3(GRID), dim3(BS), 0, stream>>>(
      in0, in1, binMinK, candVal, pCnt, pSum, segV, segS, segN, part, bar, out);
}